// Round 2
// baseline (13171.754 us; speedup 1.0000x reference)
//
#include <hip/hip_runtime.h>

#define DM 768

using u16 = unsigned short;
using u32 = unsigned int;

typedef __attribute__((ext_vector_type(8))) __bf16 bf16x8;
typedef __attribute__((ext_vector_type(4))) float f32x4;
typedef __attribute__((address_space(1))) void gvoid;
typedef __attribute__((address_space(3))) void lvoid;

__device__ __forceinline__ float bf2f(u16 h) { return __uint_as_float(((u32)h) << 16); }
__device__ __forceinline__ u16 f2bf(float f) {
    u32 u = __float_as_uint(f);
    u32 r = (u + 0x7FFFu + ((u >> 16) & 1u)) >> 16;
    return (u16)r;
}
__device__ __forceinline__ float gelu_f(float x) { return 0.5f * x * (1.f + erff(x * 0.70710678118f)); }

// ---------------- weight prep: W[768,768] f32 -> Wt[768,768] bf16 (transposed) ----------------
__global__ __launch_bounds__(256) void prep_weights(
    const float* __restrict__ aw1, const float* __restrict__ aw2,
    const float* __restrict__ bw1, const float* __restrict__ bw2,
    const float* __restrict__ cw1, const float* __restrict__ cw2,
    u16* __restrict__ wbt)
{
    int z = blockIdx.z;
    const float* W;
    if (z == 0) W = aw1;
    else if (z == 1) W = aw2;
    else if (z == 2) W = bw1;
    else if (z == 3) W = bw2;
    else if (z < 8) W = cw1 + (size_t)(z - 4) * DM * DM;
    else W = cw2 + (size_t)(z - 8) * DM * DM;
    u16* out = wbt + (size_t)z * DM * DM;

    __shared__ float tile[32][33];
    int bx = blockIdx.x * 32, by = blockIdx.y * 32; // bx: n (cols of W), by: k (rows of W)
    int tx = threadIdx.x & 31, ty = threadIdx.x >> 5;
    #pragma unroll
    for (int i = ty; i < 32; i += 8) tile[i][tx] = W[(size_t)(by + i) * DM + bx + tx];
    __syncthreads();
    #pragma unroll
    for (int i = ty; i < 32; i += 8) out[(size_t)(bx + i) * DM + by + tx] = f2bf(tile[tx][i]);
}

// ---------------- embedding sum + LayerNorm -> bf16 ----------------
__global__ __launch_bounds__(256) void encode_ln(
    const int* __restrict__ idx, int nf, int vocab,
    const float* __restrict__ emb, const float* __restrict__ g, const float* __restrict__ bb,
    u16* __restrict__ out)
{
    long n = blockIdx.x;
    int t = threadIdx.x;
    __shared__ int feat[16];
    __shared__ float sred[16];
    if (t < nf) feat[t] = idx[n * nf + t];
    __syncthreads();
    float v[3];
    float s = 0.f, s2 = 0.f;
    #pragma unroll
    for (int j = 0; j < 3; j++) {
        int d = t + j * 256;
        float a = 0.f;
        for (int f = 0; f < nf; f++) a += emb[((long)f * vocab + feat[f]) * DM + d];
        v[j] = a; s += a; s2 += a * a;
    }
    #pragma unroll
    for (int o = 32; o; o >>= 1) { s += __shfl_down(s, o); s2 += __shfl_down(s2, o); }
    int wid = t >> 6;
    if ((t & 63) == 0) { sred[wid] = s; sred[8 + wid] = s2; }
    __syncthreads();
    if (t == 0) {
        sred[0] = sred[0] + sred[1] + sred[2] + sred[3];
        sred[8] = sred[8] + sred[9] + sred[10] + sred[11];
    }
    __syncthreads();
    float mean = sred[0] * (1.f / 768.f);
    float var = sred[8] * (1.f / 768.f) - mean * mean;
    float rstd = rsqrtf(var + 1e-5f);
    #pragma unroll
    for (int j = 0; j < 3; j++) {
        int d = t + j * 256;
        out[n * DM + d] = f2bf((v[j] - mean) * rstd * g[d] + bb[d]);
    }
}

// ---------------- post-layer: t = y + h_old(bf16); LN; write h_b(optional) + f32 out (in-place on y ok) ----------------
__global__ __launch_bounds__(256) void layer_ln(
    const float* __restrict__ y, const u16* __restrict__ holdb,
    const float* __restrict__ g, const float* __restrict__ bb,
    u16* __restrict__ hb, float* __restrict__ outf)
{
    long n = blockIdx.x;
    int t = threadIdx.x;
    __shared__ float sred[16];
    float v[3];
    float s = 0.f, s2 = 0.f;
    #pragma unroll
    for (int j = 0; j < 3; j++) {
        long off = n * DM + t + j * 256;
        float a = y[off] + bf2f(holdb[off]);
        v[j] = a; s += a; s2 += a * a;
    }
    #pragma unroll
    for (int o = 32; o; o >>= 1) { s += __shfl_down(s, o); s2 += __shfl_down(s2, o); }
    int wid = t >> 6;
    if ((t & 63) == 0) { sred[wid] = s; sred[8 + wid] = s2; }
    __syncthreads();
    if (t == 0) {
        sred[0] = sred[0] + sred[1] + sred[2] + sred[3];
        sred[8] = sred[8] + sred[9] + sred[10] + sred[11];
    }
    __syncthreads();
    float mean = sred[0] * (1.f / 768.f);
    float var = sred[8] * (1.f / 768.f) - mean * mean;
    float rstd = rsqrtf(var + 1e-5f);
    #pragma unroll
    for (int j = 0; j < 3; j++) {
        int d = t + j * 256;
        long off = n * DM + d;
        float r = (v[j] - mean) * rstd * g[d] + bb[d];
        outf[off] = r;
        if (hb) hb[off] = f2bf(r);
    }
}

// ---------------- edge scatter: aggr[dst] += relu(h[src] + e) ----------------
__global__ __launch_bounds__(256) void scatter_msg(
    const u16* __restrict__ h, const u16* __restrict__ e,
    const int* __restrict__ src, const int* __restrict__ dst,
    float* __restrict__ aggr, int E)
{
    int eid = blockIdx.x * 4 + (threadIdx.x >> 6);
    if (eid >= E) return;
    int l = threadIdx.x & 63;
    long s = src[eid], d = dst[eid];
    const u16* hr = h + s * DM;
    const u16* er = e + (long)eid * DM;
    float* ar = aggr + d * DM;
    #pragma unroll
    for (int i = 0; i < 3; i++) {
        int c = i * 256 + l * 4;
        ushort4 hv = *reinterpret_cast<const ushort4*>(hr + c);
        ushort4 ev = *reinterpret_cast<const ushort4*>(er + c);
        float m0 = fmaxf(0.f, bf2f(hv.x) + bf2f(ev.x));
        float m1 = fmaxf(0.f, bf2f(hv.y) + bf2f(ev.y));
        float m2 = fmaxf(0.f, bf2f(hv.z) + bf2f(ev.z));
        float m3 = fmaxf(0.f, bf2f(hv.w) + bf2f(ev.w));
        atomicAdd(ar + c + 0, m0);
        atomicAdd(ar + c + 1, m1);
        atomicAdd(ar + c + 2, m2);
        atomicAdd(ar + c + 3, m3);
    }
}

// ---------------- f32 -> bf16 convert ----------------
__global__ __launch_bounds__(256) void conv_f2b(const float* __restrict__ in, u16* __restrict__ out, long n4)
{
    long i = (long)blockIdx.x * 256 + threadIdx.x;
    if (i >= n4) return;
    float4 v = reinterpret_cast<const float4*>(in)[i];
    ushort4 o;
    o.x = f2bf(v.x); o.y = f2bf(v.y); o.z = f2bf(v.z); o.w = f2bf(v.w);
    reinterpret_cast<ushort4*>(out)[i] = o;
}

// ---------------- GEMM: C[M,768] = act(A[M,768] @ W + bias) ; A bf16, Bt = W^T bf16 ----------------
// ACT: 0 none, 1 relu, 2 gelu.
// OUTM: 0 bf16 out (unguarded, workspace-sized); 1 f32 out guarded by Mvalid; 2 both.
template <int ACT, int OUTM>
__global__ __launch_bounds__(256) void gemm128(
    const u16* __restrict__ A, const u16* __restrict__ Bt,
    const float* __restrict__ bias,
    u16* __restrict__ outB, float* __restrict__ outF, int Mvalid)
{
    __shared__ u16 Asm[2][128 * 32];
    __shared__ u16 Bsm[2][128 * 32];
    const int tid = threadIdx.x;
    const int lane = tid & 63, wid = tid >> 6;
    const int wr = wid >> 1, wc = wid & 1;
    const long m0 = (long)blockIdx.y * 128;
    const int n0 = blockIdx.x * 128;

    f32x4 acc[4][4] = {};

    // staging: tile is 128 rows x 32 cols bf16 = 512 chunks of 16B; 2 chunks/thread
    const int ch0 = tid, ch1 = 256 + tid;
    const u16* Ag0 = A + (m0 + (ch0 >> 2)) * DM + (ch0 & 3) * 8;
    const u16* Ag1 = A + (m0 + (ch1 >> 2)) * DM + (ch1 & 3) * 8;
    const u16* Bg0 = Bt + (long)(n0 + (ch0 >> 2)) * DM + (ch0 & 3) * 8;
    const u16* Bg1 = Bt + (long)(n0 + (ch1 >> 2)) * DM + (ch1 & 3) * 8;
    const int lds0 = ((wid << 6)) * 8;        // wave-uniform element offset, call 0
    const int lds1 = (256 + (wid << 6)) * 8;  // call 1

    auto stage = [&](int buf, int kt) {
        int ko = kt * 32;
        __builtin_amdgcn_global_load_lds((gvoid*)(Ag0 + ko), (lvoid*)&Asm[buf][lds0], 16, 0, 0);
        __builtin_amdgcn_global_load_lds((gvoid*)(Ag1 + ko), (lvoid*)&Asm[buf][lds1], 16, 0, 0);
        __builtin_amdgcn_global_load_lds((gvoid*)(Bg0 + ko), (lvoid*)&Bsm[buf][lds0], 16, 0, 0);
        __builtin_amdgcn_global_load_lds((gvoid*)(Bg1 + ko), (lvoid*)&Bsm[buf][lds1], 16, 0, 0);
    };

    stage(0, 0);
    asm volatile("s_waitcnt vmcnt(0)" ::: "memory");
    __syncthreads();

    const int ar = lane & 15, kb = lane >> 4;
    int cur = 0;
    for (int kt = 0; kt < DM / 32; ++kt) {
        if (kt + 1 < DM / 32) stage(cur ^ 1, kt + 1);
        bf16x8 af[4], bv[4];
        #pragma unroll
        for (int m = 0; m < 4; m++)
            af[m] = *reinterpret_cast<const bf16x8*>(&Asm[cur][(wr * 64 + m * 16 + ar) * 32 + kb * 8]);
        #pragma unroll
        for (int n = 0; n < 4; n++)
            bv[n] = *reinterpret_cast<const bf16x8*>(&Bsm[cur][(wc * 64 + n * 16 + ar) * 32 + kb * 8]);
        #pragma unroll
        for (int m = 0; m < 4; m++)
            #pragma unroll
            for (int n = 0; n < 4; n++)
                acc[m][n] = __builtin_amdgcn_mfma_f32_16x16x32_bf16(af[m], bv[n], acc[m][n], 0, 0, 0);
        asm volatile("s_waitcnt vmcnt(0)" ::: "memory");
        __syncthreads();
        cur ^= 1;
    }

    const int rg4 = (lane >> 4) * 4;
    #pragma unroll
    for (int n = 0; n < 4; n++) {
        int col = n0 + wc * 64 + n * 16 + ar;
        float bvp = bias[col];
        #pragma unroll
        for (int m = 0; m < 4; m++) {
            long rb = m0 + wr * 64 + m * 16 + rg4;
            #pragma unroll
            for (int j = 0; j < 4; j++) {
                float v = acc[m][n][j] + bvp;
                if (ACT == 1) v = fmaxf(v, 0.f);
                if (ACT == 2) v = gelu_f(v);
                long row = rb + j;
                long off = row * DM + col;
                if (OUTM == 0) outB[off] = f2bf(v);
                if (OUTM == 1) { if (row < Mvalid) outF[off] = v; }
                if (OUTM == 2) { outB[off] = f2bf(v); if (row < Mvalid) outF[off] = v; }
            }
        }
    }
}

extern "C" void kernel_launch(void* const* d_in, const int* in_sizes, int n_in,
                              void* d_out, int out_size, void* d_ws, size_t ws_size,
                              hipStream_t stream)
{
    const int N = in_sizes[0] / 9;
    const int E = in_sizes[1] / 3;
    const int L = 4;
    const long Mpad = ((N + 127) / 128) * 128;
    const long Epad = ((E + 127) / 128) * 128;
    const int Mtiles = (int)(Mpad / 128), Etiles = (int)(Epad / 128);

    const int* x = (const int*)d_in[0];
    const int* eattr = (const int*)d_in[1];
    const int* eidx = (const int*)d_in[2];
    const float* atom_emb = (const float*)d_in[3];
    const float* atom_g = (const float*)d_in[4];
    const float* atom_bb = (const float*)d_in[5];
    const float* atom_w1 = (const float*)d_in[6];
    const float* atom_b1 = (const float*)d_in[7];
    const float* atom_w2 = (const float*)d_in[8];
    const float* atom_b2 = (const float*)d_in[9];
    const float* bond_emb = (const float*)d_in[10];
    const float* bond_g = (const float*)d_in[11];
    const float* bond_bb = (const float*)d_in[12];
    const float* bond_w1 = (const float*)d_in[13];
    const float* bond_b1 = (const float*)d_in[14];
    const float* bond_w2 = (const float*)d_in[15];
    const float* bond_b2 = (const float*)d_in[16];
    const float* conv_w1 = (const float*)d_in[17];
    const float* conv_b1 = (const float*)d_in[18];
    const float* conv_w2 = (const float*)d_in[19];
    const float* conv_b2 = (const float*)d_in[20];
    const float* ln_g = (const float*)d_in[21];
    const float* ln_b = (const float*)d_in[22];
    const int* src = eidx;
    const int* dst = eidx + E;
    float* nodeF = (float*)d_out;   // node-f32 buffer: aggr target, GEMM f32 out, final output

    // workspace: B1 (E bf16) = e_b home; B2 (max(Epad,2*Mpad) bf16) = ping-pong temps;
    // h_b (N bf16 residual); wbt (12 transposed bf16 weights).  ~783 MB total.
    char* p = (char*)d_ws;
    auto alloc = [&](size_t bytes) { void* r = (void*)p; p += (bytes + 255) & ~(size_t)255; return r; };
    const long B2rows = (Epad > 2 * Mpad) ? Epad : 2 * Mpad;
    u16* B1  = (u16*)alloc((size_t)Epad * DM * 2);
    u16* B2  = (u16*)alloc((size_t)B2rows * DM * 2);
    u16* h_b = (u16*)alloc((size_t)Mpad * DM * 2);
    u16* wbt = (u16*)alloc((size_t)12 * DM * DM * 2);
    u16* B2a = B2;
    u16* B2b = B2 + (size_t)Mpad * DM;

    // weight prep (12 matrices, transpose + bf16)
    prep_weights<<<dim3(24, 24, 12), 256, 0, stream>>>(atom_w1, atom_w2, bond_w1, bond_w2, conv_w1, conv_w2, wbt);

    // bond encoder: emb-sum+LN -> B1; GEMM1(gelu) B1->B2; GEMM2(none) B2->B1 (= e_b)
    encode_ln<<<E, 256, 0, stream>>>(eattr, 3, 8, bond_emb, bond_g, bond_bb, B1);
    gemm128<2, 0><<<dim3(6, Etiles), 256, 0, stream>>>(B1, wbt + (size_t)2 * DM * DM, bond_b1, B2, nullptr, 0);
    gemm128<0, 0><<<dim3(6, Etiles), 256, 0, stream>>>(B2, wbt + (size_t)3 * DM * DM, bond_b2, B1, nullptr, 0);

    // atom encoder: emb-sum+LN -> B2a; GEMM1(gelu) B2a->B2b; GEMM2 -> h_b (bf16) + nodeF (f32 aggr-init, guarded)
    encode_ln<<<N, 256, 0, stream>>>(x, 9, 64, atom_emb, atom_g, atom_bb, B2a);
    gemm128<2, 0><<<dim3(6, Mtiles), 256, 0, stream>>>(B2a, wbt + (size_t)0 * DM * DM, atom_b1, B2b, nullptr, 0);
    gemm128<0, 2><<<dim3(6, Mtiles), 256, 0, stream>>>(B2b, wbt + (size_t)1 * DM * DM, atom_b2, h_b, nodeF, N);

    // GNN layers
    for (int l = 0; l < L; l++) {
        scatter_msg<<<(E + 3) / 4, 256, 0, stream>>>(h_b, B1, src, dst, nodeF, E);
        conv_f2b<<<(int)(((long)N * DM / 4 + 255) / 256), 256, 0, stream>>>(nodeF, B2a, (long)N * DM / 4);
        gemm128<1, 0><<<dim3(6, Mtiles), 256, 0, stream>>>(B2a, wbt + (size_t)(4 + l) * DM * DM, conv_b1 + l * DM, B2b, nullptr, 0);
        gemm128<2, 1><<<dim3(6, Mtiles), 256, 0, stream>>>(B2b, wbt + (size_t)(8 + l) * DM * DM, conv_b2 + l * DM, nullptr, nodeF, N);
        layer_ln<<<N, 256, 0, stream>>>(nodeF, h_b, ln_g + l * DM, ln_b + l * DM,
                                        (l == L - 1) ? nullptr : h_b, nodeF);
    }
}

// Round 3
// 5617.034 us; speedup vs baseline: 2.3450x; 2.3450x over previous
//
#include <hip/hip_runtime.h>

#define DM 768
#define SCAN_BS 1024

using u16 = unsigned short;
using u32 = unsigned int;

typedef __attribute__((ext_vector_type(8))) __bf16 bf16x8;
typedef __attribute__((ext_vector_type(4))) float f32x4;
typedef __attribute__((address_space(1))) void gvoid;
typedef __attribute__((address_space(3))) void lvoid;

__device__ __forceinline__ float bf2f(u16 h) { return __uint_as_float(((u32)h) << 16); }
__device__ __forceinline__ u16 f2bf(float f) {
    u32 u = __float_as_uint(f);
    u32 r = (u + 0x7FFFu + ((u >> 16) & 1u)) >> 16;
    return (u16)r;
}
__device__ __forceinline__ float gelu_f(float x) { return 0.5f * x * (1.f + erff(x * 0.70710678118f)); }

// ---------------- weight prep: W[768,768] f32 -> Wt[768,768] bf16 (transposed) ----------------
__global__ __launch_bounds__(256) void prep_weights(
    const float* __restrict__ aw1, const float* __restrict__ aw2,
    const float* __restrict__ bw1, const float* __restrict__ bw2,
    const float* __restrict__ cw1, const float* __restrict__ cw2,
    u16* __restrict__ wbt)
{
    int z = blockIdx.z;
    const float* W;
    if (z == 0) W = aw1;
    else if (z == 1) W = aw2;
    else if (z == 2) W = bw1;
    else if (z == 3) W = bw2;
    else if (z < 8) W = cw1 + (size_t)(z - 4) * DM * DM;
    else W = cw2 + (size_t)(z - 8) * DM * DM;
    u16* out = wbt + (size_t)z * DM * DM;

    __shared__ float tile[32][33];
    int bx = blockIdx.x * 32, by = blockIdx.y * 32;
    int tx = threadIdx.x & 31, ty = threadIdx.x >> 5;
    #pragma unroll
    for (int i = ty; i < 32; i += 8) tile[i][tx] = W[(size_t)(by + i) * DM + bx + tx];
    __syncthreads();
    #pragma unroll
    for (int i = ty; i < 32; i += 8) out[(size_t)(bx + i) * DM + by + tx] = f2bf(tile[tx][i]);
}

// ---------------- embedding sum + LayerNorm -> bf16 ----------------
__global__ __launch_bounds__(256) void encode_ln(
    const int* __restrict__ idx, int nf, int vocab,
    const float* __restrict__ emb, const float* __restrict__ g, const float* __restrict__ bb,
    u16* __restrict__ out)
{
    long n = blockIdx.x;
    int t = threadIdx.x;
    __shared__ int feat[16];
    __shared__ float sred[16];
    if (t < nf) feat[t] = idx[n * nf + t];
    __syncthreads();
    float v[3];
    float s = 0.f, s2 = 0.f;
    #pragma unroll
    for (int j = 0; j < 3; j++) {
        int d = t + j * 256;
        float a = 0.f;
        for (int f = 0; f < nf; f++) a += emb[((long)f * vocab + feat[f]) * DM + d];
        v[j] = a; s += a; s2 += a * a;
    }
    #pragma unroll
    for (int o = 32; o; o >>= 1) { s += __shfl_down(s, o); s2 += __shfl_down(s2, o); }
    int wid = t >> 6;
    if ((t & 63) == 0) { sred[wid] = s; sred[8 + wid] = s2; }
    __syncthreads();
    if (t == 0) {
        sred[0] = sred[0] + sred[1] + sred[2] + sred[3];
        sred[8] = sred[8] + sred[9] + sred[10] + sred[11];
    }
    __syncthreads();
    float mean = sred[0] * (1.f / 768.f);
    float var = sred[8] * (1.f / 768.f) - mean * mean;
    float rstd = rsqrtf(var + 1e-5f);
    #pragma unroll
    for (int j = 0; j < 3; j++) {
        int d = t + j * 256;
        out[n * DM + d] = f2bf((v[j] - mean) * rstd * g[d] + bb[d]);
    }
}

// ---------------- post-layer: t = y + h_old(bf16); LN; write h_b(optional) + f32 out ----------------
__global__ __launch_bounds__(256) void layer_ln(
    const float* __restrict__ y, const u16* __restrict__ holdb,
    const float* __restrict__ g, const float* __restrict__ bb,
    u16* __restrict__ hb, float* __restrict__ outf)
{
    long n = blockIdx.x;
    int t = threadIdx.x;
    __shared__ float sred[16];
    float v[3];
    float s = 0.f, s2 = 0.f;
    #pragma unroll
    for (int j = 0; j < 3; j++) {
        long off = n * DM + t + j * 256;
        float a = y[off] + bf2f(holdb[off]);
        v[j] = a; s += a; s2 += a * a;
    }
    #pragma unroll
    for (int o = 32; o; o >>= 1) { s += __shfl_down(s, o); s2 += __shfl_down(s2, o); }
    int wid = t >> 6;
    if ((t & 63) == 0) { sred[wid] = s; sred[8 + wid] = s2; }
    __syncthreads();
    if (t == 0) {
        sred[0] = sred[0] + sred[1] + sred[2] + sred[3];
        sred[8] = sred[8] + sred[9] + sred[10] + sred[11];
    }
    __syncthreads();
    float mean = sred[0] * (1.f / 768.f);
    float var = sred[8] * (1.f / 768.f) - mean * mean;
    float rstd = rsqrtf(var + 1e-5f);
    #pragma unroll
    for (int j = 0; j < 3; j++) {
        int d = t + j * 256;
        long off = n * DM + d;
        float r = (v[j] - mean) * rstd * g[d] + bb[d];
        outf[off] = r;
        if (hb) hb[off] = f2bf(r);
    }
}

// ---------------- CSR build: counting sort of edges by dst ----------------
__global__ __launch_bounds__(256) void csr_count(const int* __restrict__ dst, int* __restrict__ deg, int E)
{
    int e = blockIdx.x * 256 + threadIdx.x;
    if (e < E) atomicAdd(&deg[dst[e]], 1);
}

__global__ __launch_bounds__(SCAN_BS) void scan_block(const int* __restrict__ deg, int* __restrict__ tmp,
                                                      int* __restrict__ bsum, int n)
{
    __shared__ int sh[SCAN_BS];
    int gid = blockIdx.x * SCAN_BS + threadIdx.x;
    int v = (gid < n) ? deg[gid] : 0;
    sh[threadIdx.x] = v;
    __syncthreads();
    for (int o = 1; o < SCAN_BS; o <<= 1) {
        int add = (threadIdx.x >= o) ? sh[threadIdx.x - o] : 0;
        __syncthreads();
        sh[threadIdx.x] += add;
        __syncthreads();
    }
    if (gid < n) tmp[gid] = sh[threadIdx.x];
    if (threadIdx.x == SCAN_BS - 1) bsum[blockIdx.x] = sh[SCAN_BS - 1];
}

__global__ __launch_bounds__(SCAN_BS) void scan_bsum(int* __restrict__ bsum, int nb)
{
    __shared__ int sh[SCAN_BS];
    int v = (threadIdx.x < nb) ? bsum[threadIdx.x] : 0;
    sh[threadIdx.x] = v;
    __syncthreads();
    for (int o = 1; o < SCAN_BS; o <<= 1) {
        int add = (threadIdx.x >= o) ? sh[threadIdx.x - o] : 0;
        __syncthreads();
        sh[threadIdx.x] += add;
        __syncthreads();
    }
    if (threadIdx.x < nb) bsum[threadIdx.x] = sh[threadIdx.x];
}

__global__ __launch_bounds__(256) void scan_final(const int* __restrict__ tmp, const int* __restrict__ bsum,
                                                  const int* __restrict__ deg, int* __restrict__ offs,
                                                  int* __restrict__ cursor, int n)
{
    int gid = blockIdx.x * 256 + threadIdx.x;
    if (gid >= n) return;
    int b = gid / SCAN_BS;
    int inc = tmp[gid] + (b > 0 ? bsum[b - 1] : 0);
    offs[gid + 1] = inc;
    cursor[gid] = inc - deg[gid];
    if (gid == 0) offs[0] = 0;
}

__global__ __launch_bounds__(256) void csr_fill(const int* __restrict__ dst, int* __restrict__ cursor,
                                                int* __restrict__ perm, int E)
{
    int e = blockIdx.x * 256 + threadIdx.x;
    if (e < E) {
        int p = atomicAdd(&cursor[dst[e]], 1);
        perm[p] = e;
    }
}

// ---------------- aggregation (gather side): out_b[n] = bf16( hF[n] + sum_{e: dst==n} relu(h_b[src]+e_b[e]) ) ----
__global__ __launch_bounds__(192) void aggregate(
    const u16* __restrict__ h, const u16* __restrict__ eb,
    const int* __restrict__ src, const int* __restrict__ perm, const int* __restrict__ offs,
    const float* __restrict__ hF, u16* __restrict__ out)
{
    long n = blockIdx.x;
    int t = threadIdx.x;           // 192 threads x 4 cols = 768
    int d = t * 4;
    float4 a = *reinterpret_cast<const float4*>(hF + n * DM + d);
    float acc0 = a.x, acc1 = a.y, acc2 = a.z, acc3 = a.w;
    int beg = offs[n], end = offs[n + 1];
    for (int k = beg; k < end; k++) {
        int eid = perm[k];
        long s = src[eid];
        ushort4 hv = *reinterpret_cast<const ushort4*>(h + s * DM + d);
        ushort4 ev = *reinterpret_cast<const ushort4*>(eb + (long)eid * DM + d);
        acc0 += fmaxf(0.f, bf2f(hv.x) + bf2f(ev.x));
        acc1 += fmaxf(0.f, bf2f(hv.y) + bf2f(ev.y));
        acc2 += fmaxf(0.f, bf2f(hv.z) + bf2f(ev.z));
        acc3 += fmaxf(0.f, bf2f(hv.w) + bf2f(ev.w));
    }
    ushort4 o;
    o.x = f2bf(acc0); o.y = f2bf(acc1); o.z = f2bf(acc2); o.w = f2bf(acc3);
    *reinterpret_cast<ushort4*>(out + n * DM + d) = o;
}

// ---------------- GEMM: C[M,768] = act(A[M,768] @ W + bias) ; A bf16, Bt = W^T bf16 ----------------
// ACT: 0 none, 1 relu, 2 gelu.
// OUTM: 0 bf16 out (unguarded, workspace-sized); 1 f32 out guarded by Mvalid; 2 both.
template <int ACT, int OUTM>
__global__ __launch_bounds__(256) void gemm128(
    const u16* __restrict__ A, const u16* __restrict__ Bt,
    const float* __restrict__ bias,
    u16* __restrict__ outB, float* __restrict__ outF, int Mvalid)
{
    __shared__ u16 Asm[2][128 * 32];
    __shared__ u16 Bsm[2][128 * 32];
    const int tid = threadIdx.x;
    const int lane = tid & 63, wid = tid >> 6;
    const int wr = wid >> 1, wc = wid & 1;
    const long m0 = (long)blockIdx.y * 128;
    const int n0 = blockIdx.x * 128;

    f32x4 acc[4][4] = {};

    const int ch0 = tid, ch1 = 256 + tid;
    const u16* Ag0 = A + (m0 + (ch0 >> 2)) * DM + (ch0 & 3) * 8;
    const u16* Ag1 = A + (m0 + (ch1 >> 2)) * DM + (ch1 & 3) * 8;
    const u16* Bg0 = Bt + (long)(n0 + (ch0 >> 2)) * DM + (ch0 & 3) * 8;
    const u16* Bg1 = Bt + (long)(n0 + (ch1 >> 2)) * DM + (ch1 & 3) * 8;
    const int lds0 = ((wid << 6)) * 8;
    const int lds1 = (256 + (wid << 6)) * 8;

    auto stage = [&](int buf, int kt) {
        int ko = kt * 32;
        __builtin_amdgcn_global_load_lds((gvoid*)(Ag0 + ko), (lvoid*)&Asm[buf][lds0], 16, 0, 0);
        __builtin_amdgcn_global_load_lds((gvoid*)(Ag1 + ko), (lvoid*)&Asm[buf][lds1], 16, 0, 0);
        __builtin_amdgcn_global_load_lds((gvoid*)(Bg0 + ko), (lvoid*)&Bsm[buf][lds0], 16, 0, 0);
        __builtin_amdgcn_global_load_lds((gvoid*)(Bg1 + ko), (lvoid*)&Bsm[buf][lds1], 16, 0, 0);
    };

    stage(0, 0);
    asm volatile("s_waitcnt vmcnt(0)" ::: "memory");
    __syncthreads();

    const int ar = lane & 15, kb = lane >> 4;
    int cur = 0;
    for (int kt = 0; kt < DM / 32; ++kt) {
        if (kt + 1 < DM / 32) stage(cur ^ 1, kt + 1);
        bf16x8 af[4], bv[4];
        #pragma unroll
        for (int m = 0; m < 4; m++)
            af[m] = *reinterpret_cast<const bf16x8*>(&Asm[cur][(wr * 64 + m * 16 + ar) * 32 + kb * 8]);
        #pragma unroll
        for (int n = 0; n < 4; n++)
            bv[n] = *reinterpret_cast<const bf16x8*>(&Bsm[cur][(wc * 64 + n * 16 + ar) * 32 + kb * 8]);
        #pragma unroll
        for (int m = 0; m < 4; m++)
            #pragma unroll
            for (int n = 0; n < 4; n++)
                acc[m][n] = __builtin_amdgcn_mfma_f32_16x16x32_bf16(af[m], bv[n], acc[m][n], 0, 0, 0);
        asm volatile("s_waitcnt vmcnt(0)" ::: "memory");
        __syncthreads();
        cur ^= 1;
    }

    const int rg4 = (lane >> 4) * 4;
    #pragma unroll
    for (int n = 0; n < 4; n++) {
        int col = n0 + wc * 64 + n * 16 + ar;
        float bvp = bias[col];
        #pragma unroll
        for (int m = 0; m < 4; m++) {
            long rb = m0 + wr * 64 + m * 16 + rg4;
            #pragma unroll
            for (int j = 0; j < 4; j++) {
                float v = acc[m][n][j] + bvp;
                if (ACT == 1) v = fmaxf(v, 0.f);
                if (ACT == 2) v = gelu_f(v);
                long row = rb + j;
                long off = row * DM + col;
                if (OUTM == 0) outB[off] = f2bf(v);
                if (OUTM == 1) { if (row < Mvalid) outF[off] = v; }
                if (OUTM == 2) { outB[off] = f2bf(v); if (row < Mvalid) outF[off] = v; }
            }
        }
    }
}

extern "C" void kernel_launch(void* const* d_in, const int* in_sizes, int n_in,
                              void* d_out, int out_size, void* d_ws, size_t ws_size,
                              hipStream_t stream)
{
    const int N = in_sizes[0] / 9;
    const int E = in_sizes[1] / 3;
    const int L = 4;
    const long Mpad = ((N + 127) / 128) * 128;
    const long Epad = ((E + 127) / 128) * 128;
    const int Mtiles = (int)(Mpad / 128), Etiles = (int)(Epad / 128);

    const int* x = (const int*)d_in[0];
    const int* eattr = (const int*)d_in[1];
    const int* eidx = (const int*)d_in[2];
    const float* atom_emb = (const float*)d_in[3];
    const float* atom_g = (const float*)d_in[4];
    const float* atom_bb = (const float*)d_in[5];
    const float* atom_w1 = (const float*)d_in[6];
    const float* atom_b1 = (const float*)d_in[7];
    const float* atom_w2 = (const float*)d_in[8];
    const float* atom_b2 = (const float*)d_in[9];
    const float* bond_emb = (const float*)d_in[10];
    const float* bond_g = (const float*)d_in[11];
    const float* bond_bb = (const float*)d_in[12];
    const float* bond_w1 = (const float*)d_in[13];
    const float* bond_b1 = (const float*)d_in[14];
    const float* bond_w2 = (const float*)d_in[15];
    const float* bond_b2 = (const float*)d_in[16];
    const float* conv_w1 = (const float*)d_in[17];
    const float* conv_b1 = (const float*)d_in[18];
    const float* conv_w2 = (const float*)d_in[19];
    const float* conv_b2 = (const float*)d_in[20];
    const float* ln_g = (const float*)d_in[21];
    const float* ln_b = (const float*)d_in[22];
    const int* src = eidx;
    const int* dst = eidx + E;
    float* nodeF = (float*)d_out;   // node-f32 buffer: f32 h / GEMM f32 out, final output

    char* p = (char*)d_ws;
    auto alloc = [&](size_t bytes) { void* r = (void*)p; p += (bytes + 255) & ~(size_t)255; return r; };
    const long B2rows = (Epad > 2 * Mpad) ? Epad : 2 * Mpad;
    u16* B1  = (u16*)alloc((size_t)Epad * DM * 2);
    u16* B2  = (u16*)alloc((size_t)B2rows * DM * 2);
    u16* h_b = (u16*)alloc((size_t)Mpad * DM * 2);
    u16* wbt = (u16*)alloc((size_t)12 * DM * DM * 2);
    int* deg    = (int*)alloc((size_t)N * 4);
    int* tmp    = (int*)alloc((size_t)N * 4);
    int* cursor = (int*)alloc((size_t)N * 4);
    int* offs   = (int*)alloc((size_t)(N + 1) * 4);
    int* bsum   = (int*)alloc((size_t)SCAN_BS * 4);
    int* perm   = (int*)alloc((size_t)E * 4);
    u16* B2a = B2;
    u16* B2b = B2 + (size_t)Mpad * DM;

    // ---- CSR build (counting sort by dst) ----
    hipMemsetAsync(deg, 0, (size_t)N * 4, stream);
    csr_count<<<(E + 255) / 256, 256, 0, stream>>>(dst, deg, E);
    const int nb = (N + SCAN_BS - 1) / SCAN_BS;
    scan_block<<<nb, SCAN_BS, 0, stream>>>(deg, tmp, bsum, N);
    scan_bsum<<<1, SCAN_BS, 0, stream>>>(bsum, nb);
    scan_final<<<(N + 255) / 256, 256, 0, stream>>>(tmp, bsum, deg, offs, cursor, N);
    csr_fill<<<(E + 255) / 256, 256, 0, stream>>>(dst, cursor, perm, E);

    // weight prep (12 matrices, transpose + bf16)
    prep_weights<<<dim3(24, 24, 12), 256, 0, stream>>>(atom_w1, atom_w2, bond_w1, bond_w2, conv_w1, conv_w2, wbt);

    // bond encoder: emb-sum+LN -> B1; GEMM1(gelu) B1->B2; GEMM2(none) B2->B1 (= e_b)
    encode_ln<<<E, 256, 0, stream>>>(eattr, 3, 8, bond_emb, bond_g, bond_bb, B1);
    gemm128<2, 0><<<dim3(6, Etiles), 256, 0, stream>>>(B1, wbt + (size_t)2 * DM * DM, bond_b1, B2, nullptr, 0);
    gemm128<0, 0><<<dim3(6, Etiles), 256, 0, stream>>>(B2, wbt + (size_t)3 * DM * DM, bond_b2, B1, nullptr, 0);

    // atom encoder: emb-sum+LN -> B2a; GEMM1(gelu) B2a->B2b; GEMM2 -> h_b (bf16) + nodeF (f32 h, guarded)
    encode_ln<<<N, 256, 0, stream>>>(x, 9, 64, atom_emb, atom_g, atom_bb, B2a);
    gemm128<2, 0><<<dim3(6, Mtiles), 256, 0, stream>>>(B2a, wbt + (size_t)0 * DM * DM, atom_b1, B2b, nullptr, 0);
    gemm128<0, 2><<<dim3(6, Mtiles), 256, 0, stream>>>(B2b, wbt + (size_t)1 * DM * DM, atom_b2, h_b, nodeF, N);

    // GNN layers
    for (int l = 0; l < L; l++) {
        aggregate<<<N, 192, 0, stream>>>(h_b, B1, src, perm, offs, nodeF, B2a);
        gemm128<1, 0><<<dim3(6, Mtiles), 256, 0, stream>>>(B2a, wbt + (size_t)(4 + l) * DM * DM, conv_b1 + l * DM, B2b, nullptr, 0);
        gemm128<2, 1><<<dim3(6, Mtiles), 256, 0, stream>>>(B2b, wbt + (size_t)(8 + l) * DM * DM, conv_b2 + l * DM, nullptr, nodeF, N);
        layer_ln<<<N, 256, 0, stream>>>(nodeF, h_b, ln_g + l * DM, ln_b + l * DM,
                                        (l == L - 1) ? nullptr : h_b, nodeF);
    }
}

// Round 4
// 5330.938 us; speedup vs baseline: 2.4708x; 1.0537x over previous
//
#include <hip/hip_runtime.h>

#define DM 768
#define SCAN_BS 1024

using u16 = unsigned short;
using u32 = unsigned int;

typedef __attribute__((ext_vector_type(8))) __bf16 bf16x8;
typedef __attribute__((ext_vector_type(4))) float f32x4;
typedef __attribute__((address_space(1))) void gvoid;
typedef __attribute__((address_space(3))) void lvoid;

__device__ __forceinline__ float bf2f(u16 h) { return __uint_as_float(((u32)h) << 16); }
__device__ __forceinline__ u16 f2bf(float f) {
    u32 u = __float_as_uint(f);
    u32 r = (u + 0x7FFFu + ((u >> 16) & 1u)) >> 16;
    return (u16)r;
}
__device__ __forceinline__ float gelu_f(float x) { return 0.5f * x * (1.f + erff(x * 0.70710678118f)); }

// ---------------- weight prep: W[768,768] f32 -> Wt[768,768] bf16 (transposed) ----------------
__global__ __launch_bounds__(256) void prep_weights(
    const float* __restrict__ aw1, const float* __restrict__ aw2,
    const float* __restrict__ bw1, const float* __restrict__ bw2,
    const float* __restrict__ cw1, const float* __restrict__ cw2,
    u16* __restrict__ wbt)
{
    int z = blockIdx.z;
    const float* W;
    if (z == 0) W = aw1;
    else if (z == 1) W = aw2;
    else if (z == 2) W = bw1;
    else if (z == 3) W = bw2;
    else if (z < 8) W = cw1 + (size_t)(z - 4) * DM * DM;
    else W = cw2 + (size_t)(z - 8) * DM * DM;
    u16* out = wbt + (size_t)z * DM * DM;

    __shared__ float tile[32][33];
    int bx = blockIdx.x * 32, by = blockIdx.y * 32;
    int tx = threadIdx.x & 31, ty = threadIdx.x >> 5;
    #pragma unroll
    for (int i = ty; i < 32; i += 8) tile[i][tx] = W[(size_t)(by + i) * DM + bx + tx];
    __syncthreads();
    #pragma unroll
    for (int i = ty; i < 32; i += 8) out[(size_t)(bx + i) * DM + by + tx] = f2bf(tile[tx][i]);
}

// ---------------- embedding sum + LayerNorm -> bf16 ----------------
__global__ __launch_bounds__(256) void encode_ln(
    const int* __restrict__ idx, int nf, int vocab,
    const float* __restrict__ emb, const float* __restrict__ g, const float* __restrict__ bb,
    u16* __restrict__ out)
{
    long n = blockIdx.x;
    int t = threadIdx.x;
    __shared__ int feat[16];
    __shared__ float sred[16];
    if (t < nf) feat[t] = idx[n * nf + t];
    __syncthreads();
    float v[3];
    float s = 0.f, s2 = 0.f;
    #pragma unroll
    for (int j = 0; j < 3; j++) {
        int d = t + j * 256;
        float a = 0.f;
        for (int f = 0; f < nf; f++) a += emb[((long)f * vocab + feat[f]) * DM + d];
        v[j] = a; s += a; s2 += a * a;
    }
    #pragma unroll
    for (int o = 32; o; o >>= 1) { s += __shfl_down(s, o); s2 += __shfl_down(s2, o); }
    int wid = t >> 6;
    if ((t & 63) == 0) { sred[wid] = s; sred[8 + wid] = s2; }
    __syncthreads();
    if (t == 0) {
        sred[0] = sred[0] + sred[1] + sred[2] + sred[3];
        sred[8] = sred[8] + sred[9] + sred[10] + sred[11];
    }
    __syncthreads();
    float mean = sred[0] * (1.f / 768.f);
    float var = sred[8] * (1.f / 768.f) - mean * mean;
    float rstd = rsqrtf(var + 1e-5f);
    #pragma unroll
    for (int j = 0; j < 3; j++) {
        int d = t + j * 256;
        out[n * DM + d] = f2bf((v[j] - mean) * rstd * g[d] + bb[d]);
    }
}

// ---------------- post-layer: t = y + h_old(bf16); LN; write h_b(optional) + f32 out ----------------
__global__ __launch_bounds__(256) void layer_ln(
    const float* __restrict__ y, const u16* __restrict__ holdb,
    const float* __restrict__ g, const float* __restrict__ bb,
    u16* __restrict__ hb, float* __restrict__ outf)
{
    long n = blockIdx.x;
    int t = threadIdx.x;
    __shared__ float sred[16];
    float v[3];
    float s = 0.f, s2 = 0.f;
    #pragma unroll
    for (int j = 0; j < 3; j++) {
        long off = n * DM + t + j * 256;
        float a = y[off] + bf2f(holdb[off]);
        v[j] = a; s += a; s2 += a * a;
    }
    #pragma unroll
    for (int o = 32; o; o >>= 1) { s += __shfl_down(s, o); s2 += __shfl_down(s2, o); }
    int wid = t >> 6;
    if ((t & 63) == 0) { sred[wid] = s; sred[8 + wid] = s2; }
    __syncthreads();
    if (t == 0) {
        sred[0] = sred[0] + sred[1] + sred[2] + sred[3];
        sred[8] = sred[8] + sred[9] + sred[10] + sred[11];
    }
    __syncthreads();
    float mean = sred[0] * (1.f / 768.f);
    float var = sred[8] * (1.f / 768.f) - mean * mean;
    float rstd = rsqrtf(var + 1e-5f);
    #pragma unroll
    for (int j = 0; j < 3; j++) {
        int d = t + j * 256;
        long off = n * DM + d;
        float r = (v[j] - mean) * rstd * g[d] + bb[d];
        outf[off] = r;
        if (hb) hb[off] = f2bf(r);
    }
}

// ---------------- CSR build: counting sort of edges by dst ----------------
__global__ __launch_bounds__(256) void csr_count(const int* __restrict__ dst, int* __restrict__ deg, int E)
{
    int e = blockIdx.x * 256 + threadIdx.x;
    if (e < E) atomicAdd(&deg[dst[e]], 1);
}

__global__ __launch_bounds__(SCAN_BS) void scan_block(const int* __restrict__ deg, int* __restrict__ tmp,
                                                      int* __restrict__ bsum, int n)
{
    __shared__ int sh[SCAN_BS];
    int gid = blockIdx.x * SCAN_BS + threadIdx.x;
    int v = (gid < n) ? deg[gid] : 0;
    sh[threadIdx.x] = v;
    __syncthreads();
    for (int o = 1; o < SCAN_BS; o <<= 1) {
        int add = (threadIdx.x >= o) ? sh[threadIdx.x - o] : 0;
        __syncthreads();
        sh[threadIdx.x] += add;
        __syncthreads();
    }
    if (gid < n) tmp[gid] = sh[threadIdx.x];
    if (threadIdx.x == SCAN_BS - 1) bsum[blockIdx.x] = sh[SCAN_BS - 1];
}

__global__ __launch_bounds__(SCAN_BS) void scan_bsum(int* __restrict__ bsum, int nb)
{
    __shared__ int sh[SCAN_BS];
    int v = (threadIdx.x < nb) ? bsum[threadIdx.x] : 0;
    sh[threadIdx.x] = v;
    __syncthreads();
    for (int o = 1; o < SCAN_BS; o <<= 1) {
        int add = (threadIdx.x >= o) ? sh[threadIdx.x - o] : 0;
        __syncthreads();
        sh[threadIdx.x] += add;
        __syncthreads();
    }
    if (threadIdx.x < nb) bsum[threadIdx.x] = sh[threadIdx.x];
}

__global__ __launch_bounds__(256) void scan_final(const int* __restrict__ tmp, const int* __restrict__ bsum,
                                                  const int* __restrict__ deg, int* __restrict__ offs,
                                                  int* __restrict__ cursor, int n)
{
    int gid = blockIdx.x * 256 + threadIdx.x;
    if (gid >= n) return;
    int b = gid / SCAN_BS;
    int inc = tmp[gid] + (b > 0 ? bsum[b - 1] : 0);
    offs[gid + 1] = inc;
    cursor[gid] = inc - deg[gid];
    if (gid == 0) offs[0] = 0;
}

__global__ __launch_bounds__(256) void csr_fill(const int* __restrict__ dst, int* __restrict__ cursor,
                                                int* __restrict__ perm, int E)
{
    int e = blockIdx.x * 256 + threadIdx.x;
    if (e < E) {
        int p = atomicAdd(&cursor[dst[e]], 1);
        perm[p] = e;
    }
}

// ---------------- aggregation (gather side): out_b[n] = bf16( hF[n] + sum_{e: dst==n} relu(h_b[src]+e_b[e]) ) ----
__global__ __launch_bounds__(192) void aggregate(
    const u16* __restrict__ h, const u16* __restrict__ eb,
    const int* __restrict__ src, const int* __restrict__ perm, const int* __restrict__ offs,
    const float* __restrict__ hF, u16* __restrict__ out)
{
    long n = blockIdx.x;
    int t = threadIdx.x;           // 192 threads x 4 cols = 768
    int d = t * 4;
    float4 a = *reinterpret_cast<const float4*>(hF + n * DM + d);
    float acc0 = a.x, acc1 = a.y, acc2 = a.z, acc3 = a.w;
    int beg = offs[n], end = offs[n + 1];
    for (int k = beg; k < end; k++) {
        int eid = perm[k];
        long s = src[eid];
        ushort4 hv = *reinterpret_cast<const ushort4*>(h + s * DM + d);
        ushort4 ev = *reinterpret_cast<const ushort4*>(eb + (long)eid * DM + d);
        acc0 += fmaxf(0.f, bf2f(hv.x) + bf2f(ev.x));
        acc1 += fmaxf(0.f, bf2f(hv.y) + bf2f(ev.y));
        acc2 += fmaxf(0.f, bf2f(hv.z) + bf2f(ev.z));
        acc3 += fmaxf(0.f, bf2f(hv.w) + bf2f(ev.w));
    }
    ushort4 o;
    o.x = f2bf(acc0); o.y = f2bf(acc1); o.z = f2bf(acc2); o.w = f2bf(acc3);
    *reinterpret_cast<ushort4*>(out + n * DM + d) = o;
}

// ---------------- GEMM: C[M,768] = act(A[M,768] @ W + bias) ; A bf16, Bt = W^T bf16 ----------------
// ACT: 0 none, 1 relu, 2 gelu.
// OUTM: 0 bf16 out (unguarded, workspace-sized); 1 f32 out guarded by Mvalid; 2 both.
// 1D grid of 6*Mtiles blocks; XCD-chunked bijective swizzle; n-tile fastest within chunk.
// LDS tile [row][4 kb-chunks of 16B], kb XOR-swizzled by (row>>1)&3 (source + read, dest linear).
template <int ACT, int OUTM>
__global__ __launch_bounds__(256) void gemm128(
    const u16* __restrict__ A, const u16* __restrict__ Bt,
    const float* __restrict__ bias,
    u16* __restrict__ outB, float* __restrict__ outF, int Mvalid)
{
    __shared__ u16 Asm[2][128 * 32];
    __shared__ u16 Bsm[2][128 * 32];
    const int tid = threadIdx.x;
    const int lane = tid & 63, wid = tid >> 6;
    const int wr = wid >> 1, wc = wid & 1;

    // XCD-chunked bijective block swizzle (m204)
    const int nwg = gridDim.x;
    const int orig = blockIdx.x;
    const int q8 = nwg >> 3, r8 = nwg & 7;
    const int xcd = orig & 7, idx8 = orig >> 3;
    const int w = (xcd < r8 ? xcd * (q8 + 1) : r8 * (q8 + 1) + (xcd - r8) * q8) + idx8;
    const int n0 = (w % 6) * 128;
    const long m0 = (long)(w / 6) * 128;

    f32x4 acc[4][4] = {};

    // staging: 512 chunks of 16B per tile; chunk c -> row=c>>2, kb_phys=c&3.
    // source reads logical kb = kb_phys ^ ((row>>1)&3)  (XOR involution, dest linear)
    const int ch0 = tid, ch1 = 256 + tid;
    const int r0_ = ch0 >> 2, k0_ = (ch0 & 3) ^ ((r0_ >> 1) & 3);
    const int r1_ = ch1 >> 2, k1_ = (ch1 & 3) ^ ((r1_ >> 1) & 3);
    const u16* Ag0 = A + (m0 + r0_) * DM + k0_ * 8;
    const u16* Ag1 = A + (m0 + r1_) * DM + k1_ * 8;
    const u16* Bg0 = Bt + (long)(n0 + r0_) * DM + k0_ * 8;
    const u16* Bg1 = Bt + (long)(n0 + r1_) * DM + k1_ * 8;
    const int lds0 = ((wid << 6)) * 8;
    const int lds1 = (256 + (wid << 6)) * 8;

    auto stage = [&](int buf, int kt) {
        int ko = kt * 32;
        __builtin_amdgcn_global_load_lds((gvoid*)(Ag0 + ko), (lvoid*)&Asm[buf][lds0], 16, 0, 0);
        __builtin_amdgcn_global_load_lds((gvoid*)(Ag1 + ko), (lvoid*)&Asm[buf][lds1], 16, 0, 0);
        __builtin_amdgcn_global_load_lds((gvoid*)(Bg0 + ko), (lvoid*)&Bsm[buf][lds0], 16, 0, 0);
        __builtin_amdgcn_global_load_lds((gvoid*)(Bg1 + ko), (lvoid*)&Bsm[buf][lds1], 16, 0, 0);
    };

    stage(0, 0);
    asm volatile("s_waitcnt vmcnt(0)" ::: "memory");
    __syncthreads();

    const int ar = lane & 15, kb = lane >> 4;
    const int kbe = kb ^ ((ar >> 1) & 3);   // read-side XOR (m,wr-invariant)
    int cur = 0;
    for (int kt = 0; kt < DM / 32; ++kt) {
        if (kt + 1 < DM / 32) stage(cur ^ 1, kt + 1);
        bf16x8 af[4], bv[4];
        #pragma unroll
        for (int m = 0; m < 4; m++)
            af[m] = *reinterpret_cast<const bf16x8*>(&Asm[cur][(wr * 64 + m * 16 + ar) * 32 + kbe * 8]);
        #pragma unroll
        for (int n = 0; n < 4; n++)
            bv[n] = *reinterpret_cast<const bf16x8*>(&Bsm[cur][(wc * 64 + n * 16 + ar) * 32 + kbe * 8]);
        #pragma unroll
        for (int m = 0; m < 4; m++)
            #pragma unroll
            for (int n = 0; n < 4; n++)
                acc[m][n] = __builtin_amdgcn_mfma_f32_16x16x32_bf16(af[m], bv[n], acc[m][n], 0, 0, 0);
        asm volatile("s_waitcnt vmcnt(0)" ::: "memory");
        __syncthreads();
        cur ^= 1;
    }

    const int rg4 = (lane >> 4) * 4;
    #pragma unroll
    for (int n = 0; n < 4; n++) {
        int col = n0 + wc * 64 + n * 16 + ar;
        float bvp = bias[col];
        #pragma unroll
        for (int m = 0; m < 4; m++) {
            long rb = m0 + wr * 64 + m * 16 + rg4;
            #pragma unroll
            for (int j = 0; j < 4; j++) {
                float v = acc[m][n][j] + bvp;
                if (ACT == 1) v = fmaxf(v, 0.f);
                if (ACT == 2) v = gelu_f(v);
                long row = rb + j;
                long off = row * DM + col;
                if (OUTM == 0) outB[off] = f2bf(v);
                if (OUTM == 1) { if (row < Mvalid) outF[off] = v; }
                if (OUTM == 2) { outB[off] = f2bf(v); if (row < Mvalid) outF[off] = v; }
            }
        }
    }
}

extern "C" void kernel_launch(void* const* d_in, const int* in_sizes, int n_in,
                              void* d_out, int out_size, void* d_ws, size_t ws_size,
                              hipStream_t stream)
{
    const int N = in_sizes[0] / 9;
    const int E = in_sizes[1] / 3;
    const int L = 4;
    const long Mpad = ((N + 127) / 128) * 128;
    const long Epad = ((E + 127) / 128) * 128;
    const int Mtiles = (int)(Mpad / 128), Etiles = (int)(Epad / 128);

    const int* x = (const int*)d_in[0];
    const int* eattr = (const int*)d_in[1];
    const int* eidx = (const int*)d_in[2];
    const float* atom_emb = (const float*)d_in[3];
    const float* atom_g = (const float*)d_in[4];
    const float* atom_bb = (const float*)d_in[5];
    const float* atom_w1 = (const float*)d_in[6];
    const float* atom_b1 = (const float*)d_in[7];
    const float* atom_w2 = (const float*)d_in[8];
    const float* atom_b2 = (const float*)d_in[9];
    const float* bond_emb = (const float*)d_in[10];
    const float* bond_g = (const float*)d_in[11];
    const float* bond_bb = (const float*)d_in[12];
    const float* bond_w1 = (const float*)d_in[13];
    const float* bond_b1 = (const float*)d_in[14];
    const float* bond_w2 = (const float*)d_in[15];
    const float* bond_b2 = (const float*)d_in[16];
    const float* conv_w1 = (const float*)d_in[17];
    const float* conv_b1 = (const float*)d_in[18];
    const float* conv_w2 = (const float*)d_in[19];
    const float* conv_b2 = (const float*)d_in[20];
    const float* ln_g = (const float*)d_in[21];
    const float* ln_b = (const float*)d_in[22];
    const int* src = eidx;
    const int* dst = eidx + E;
    float* nodeF = (float*)d_out;   // node-f32 buffer: f32 h / GEMM f32 out, final output

    char* p = (char*)d_ws;
    auto alloc = [&](size_t bytes) { void* r = (void*)p; p += (bytes + 255) & ~(size_t)255; return r; };
    const long B2rows = (Epad > 2 * Mpad) ? Epad : 2 * Mpad;
    u16* B1  = (u16*)alloc((size_t)Epad * DM * 2);
    u16* B2  = (u16*)alloc((size_t)B2rows * DM * 2);
    u16* h_b = (u16*)alloc((size_t)Mpad * DM * 2);
    u16* wbt = (u16*)alloc((size_t)12 * DM * DM * 2);
    int* deg    = (int*)alloc((size_t)N * 4);
    int* tmp    = (int*)alloc((size_t)N * 4);
    int* cursor = (int*)alloc((size_t)N * 4);
    int* offs   = (int*)alloc((size_t)(N + 1) * 4);
    int* bsum   = (int*)alloc((size_t)SCAN_BS * 4);
    int* perm   = (int*)alloc((size_t)E * 4);
    u16* B2a = B2;
    u16* B2b = B2 + (size_t)Mpad * DM;

    // ---- CSR build (counting sort by dst) ----
    hipMemsetAsync(deg, 0, (size_t)N * 4, stream);
    csr_count<<<(E + 255) / 256, 256, 0, stream>>>(dst, deg, E);
    const int nb = (N + SCAN_BS - 1) / SCAN_BS;
    scan_block<<<nb, SCAN_BS, 0, stream>>>(deg, tmp, bsum, N);
    scan_bsum<<<1, SCAN_BS, 0, stream>>>(bsum, nb);
    scan_final<<<(N + 255) / 256, 256, 0, stream>>>(tmp, bsum, deg, offs, cursor, N);
    csr_fill<<<(E + 255) / 256, 256, 0, stream>>>(dst, cursor, perm, E);

    // weight prep (12 matrices, transpose + bf16)
    prep_weights<<<dim3(24, 24, 12), 256, 0, stream>>>(atom_w1, atom_w2, bond_w1, bond_w2, conv_w1, conv_w2, wbt);

    // bond encoder: emb-sum+LN -> B1; GEMM1(gelu) B1->B2; GEMM2(none) B2->B1 (= e_b)
    encode_ln<<<E, 256, 0, stream>>>(eattr, 3, 8, bond_emb, bond_g, bond_bb, B1);
    gemm128<2, 0><<<6 * Etiles, 256, 0, stream>>>(B1, wbt + (size_t)2 * DM * DM, bond_b1, B2, nullptr, 0);
    gemm128<0, 0><<<6 * Etiles, 256, 0, stream>>>(B2, wbt + (size_t)3 * DM * DM, bond_b2, B1, nullptr, 0);

    // atom encoder: emb-sum+LN -> B2a; GEMM1(gelu) B2a->B2b; GEMM2 -> h_b (bf16) + nodeF (f32 h, guarded)
    encode_ln<<<N, 256, 0, stream>>>(x, 9, 64, atom_emb, atom_g, atom_bb, B2a);
    gemm128<2, 0><<<6 * Mtiles, 256, 0, stream>>>(B2a, wbt + (size_t)0 * DM * DM, atom_b1, B2b, nullptr, 0);
    gemm128<0, 2><<<6 * Mtiles, 256, 0, stream>>>(B2b, wbt + (size_t)1 * DM * DM, atom_b2, h_b, nodeF, N);

    // GNN layers
    for (int l = 0; l < L; l++) {
        aggregate<<<N, 192, 0, stream>>>(h_b, B1, src, perm, offs, nodeF, B2a);
        gemm128<1, 0><<<6 * Mtiles, 256, 0, stream>>>(B2a, wbt + (size_t)(4 + l) * DM * DM, conv_b1 + l * DM, B2b, nullptr, 0);
        gemm128<2, 1><<<6 * Mtiles, 256, 0, stream>>>(B2b, wbt + (size_t)(8 + l) * DM * DM, conv_b2 + l * DM, nullptr, nodeF, N);
        layer_ln<<<N, 256, 0, stream>>>(nodeF, h_b, ln_g + l * DM, ln_b + l * DM,
                                        (l == L - 1) ? nullptr : h_b, nodeF);
    }
}

// Round 5
// 3933.434 us; speedup vs baseline: 3.3487x; 1.3553x over previous
//
#include <hip/hip_runtime.h>

#define DM 768
#define SCAN_BS 1024

using u16 = unsigned short;
using u32 = unsigned int;

typedef __attribute__((ext_vector_type(8))) __bf16 bf16x8;
typedef __attribute__((ext_vector_type(4))) float f32x4;
typedef __attribute__((address_space(1))) void gvoid;
typedef __attribute__((address_space(3))) void lvoid;

__device__ __forceinline__ float bf2f(u16 h) { return __uint_as_float(((u32)h) << 16); }
__device__ __forceinline__ u16 f2bf(float f) {
    u32 u = __float_as_uint(f);
    u32 r = (u + 0x7FFFu + ((u >> 16) & 1u)) >> 16;
    return (u16)r;
}
__device__ __forceinline__ float gelu_f(float x) { return 0.5f * x * (1.f + erff(x * 0.70710678118f)); }

// ---------------- weight prep: W[768,768] f32 -> Wt[768,768] bf16 (transposed) ----------------
__global__ __launch_bounds__(256) void prep_weights(
    const float* __restrict__ aw1, const float* __restrict__ aw2,
    const float* __restrict__ bw1, const float* __restrict__ bw2,
    const float* __restrict__ cw1, const float* __restrict__ cw2,
    u16* __restrict__ wbt)
{
    int z = blockIdx.z;
    const float* W;
    if (z == 0) W = aw1;
    else if (z == 1) W = aw2;
    else if (z == 2) W = bw1;
    else if (z == 3) W = bw2;
    else if (z < 8) W = cw1 + (size_t)(z - 4) * DM * DM;
    else W = cw2 + (size_t)(z - 8) * DM * DM;
    u16* out = wbt + (size_t)z * DM * DM;

    __shared__ float tile[32][33];
    int bx = blockIdx.x * 32, by = blockIdx.y * 32;
    int tx = threadIdx.x & 31, ty = threadIdx.x >> 5;
    #pragma unroll
    for (int i = ty; i < 32; i += 8) tile[i][tx] = W[(size_t)(by + i) * DM + bx + tx];
    __syncthreads();
    #pragma unroll
    for (int i = ty; i < 32; i += 8) out[(size_t)(bx + i) * DM + by + tx] = f2bf(tile[tx][i]);
}

// ---------------- atom embedding sum + LayerNorm -> bf16 ----------------
__global__ __launch_bounds__(256) void encode_ln(
    const int* __restrict__ idx, int nf, int vocab,
    const float* __restrict__ emb, const float* __restrict__ g, const float* __restrict__ bb,
    u16* __restrict__ out)
{
    long n = blockIdx.x;
    int t = threadIdx.x;
    __shared__ int feat[16];
    __shared__ float sred[16];
    if (t < nf) feat[t] = idx[n * nf + t];
    __syncthreads();
    float v[3];
    float s = 0.f, s2 = 0.f;
    #pragma unroll
    for (int j = 0; j < 3; j++) {
        int d = t + j * 256;
        float a = 0.f;
        for (int f = 0; f < nf; f++) a += emb[((long)f * vocab + feat[f]) * DM + d];
        v[j] = a; s += a; s2 += a * a;
    }
    #pragma unroll
    for (int o = 32; o; o >>= 1) { s += __shfl_down(s, o); s2 += __shfl_down(s2, o); }
    int wid = t >> 6;
    if ((t & 63) == 0) { sred[wid] = s; sred[8 + wid] = s2; }
    __syncthreads();
    if (t == 0) {
        sred[0] = sred[0] + sred[1] + sred[2] + sred[3];
        sred[8] = sred[8] + sred[9] + sred[10] + sred[11];
    }
    __syncthreads();
    float mean = sred[0] * (1.f / 768.f);
    float var = sred[8] * (1.f / 768.f) - mean * mean;
    float rstd = rsqrtf(var + 1e-5f);
    #pragma unroll
    for (int j = 0; j < 3; j++) {
        int d = t + j * 256;
        out[n * DM + d] = f2bf((v[j] - mean) * rstd * g[d] + bb[d]);
    }
}

// ---------------- bond table: all 512 key combos, emb-sum + LN -> bf16 ----------------
__global__ __launch_bounds__(256) void encode_ln_bond(
    const float* __restrict__ emb, const float* __restrict__ g, const float* __restrict__ bb,
    u16* __restrict__ out)
{
    int key = blockIdx.x;       // 0..511
    int t = threadIdx.x;
    __shared__ float sred[16];
    int f0 = key & 7, f1 = (key >> 3) & 7, f2 = (key >> 6) & 7;
    float v[3];
    float s = 0.f, s2 = 0.f;
    #pragma unroll
    for (int j = 0; j < 3; j++) {
        int d = t + j * 256;
        float a = emb[(0 * 8 + f0) * DM + d] + emb[(1 * 8 + f1) * DM + d] + emb[(2 * 8 + f2) * DM + d];
        v[j] = a; s += a; s2 += a * a;
    }
    #pragma unroll
    for (int o = 32; o; o >>= 1) { s += __shfl_down(s, o); s2 += __shfl_down(s2, o); }
    int wid = t >> 6;
    if ((t & 63) == 0) { sred[wid] = s; sred[8 + wid] = s2; }
    __syncthreads();
    if (t == 0) {
        sred[0] = sred[0] + sred[1] + sred[2] + sred[3];
        sred[8] = sred[8] + sred[9] + sred[10] + sred[11];
    }
    __syncthreads();
    float mean = sred[0] * (1.f / 768.f);
    float var = sred[8] * (1.f / 768.f) - mean * mean;
    float rstd = rsqrtf(var + 1e-5f);
    #pragma unroll
    for (int j = 0; j < 3; j++) {
        int d = t + j * 256;
        out[(long)key * DM + d] = f2bf((v[j] - mean) * rstd * g[d] + bb[d]);
    }
}

// ---------------- post-layer: t = y + h_old(bf16); LN; write h_b(optional) + f32 out ----------------
__global__ __launch_bounds__(256) void layer_ln(
    const float* __restrict__ y, const u16* __restrict__ holdb,
    const float* __restrict__ g, const float* __restrict__ bb,
    u16* __restrict__ hb, float* __restrict__ outf)
{
    long n = blockIdx.x;
    int t = threadIdx.x;
    __shared__ float sred[16];
    float v[3];
    float s = 0.f, s2 = 0.f;
    #pragma unroll
    for (int j = 0; j < 3; j++) {
        long off = n * DM + t + j * 256;
        float a = y[off] + bf2f(holdb[off]);
        v[j] = a; s += a; s2 += a * a;
    }
    #pragma unroll
    for (int o = 32; o; o >>= 1) { s += __shfl_down(s, o); s2 += __shfl_down(s2, o); }
    int wid = t >> 6;
    if ((t & 63) == 0) { sred[wid] = s; sred[8 + wid] = s2; }
    __syncthreads();
    if (t == 0) {
        sred[0] = sred[0] + sred[1] + sred[2] + sred[3];
        sred[8] = sred[8] + sred[9] + sred[10] + sred[11];
    }
    __syncthreads();
    float mean = sred[0] * (1.f / 768.f);
    float var = sred[8] * (1.f / 768.f) - mean * mean;
    float rstd = rsqrtf(var + 1e-5f);
    #pragma unroll
    for (int j = 0; j < 3; j++) {
        int d = t + j * 256;
        long off = n * DM + d;
        float r = (v[j] - mean) * rstd * g[d] + bb[d];
        outf[off] = r;
        if (hb) hb[off] = f2bf(r);
    }
}

// ---------------- CSR build: counting sort of edges by dst ----------------
__global__ __launch_bounds__(256) void csr_count(const int* __restrict__ dst, int* __restrict__ deg, int E)
{
    int e = blockIdx.x * 256 + threadIdx.x;
    if (e < E) atomicAdd(&deg[dst[e]], 1);
}

__global__ __launch_bounds__(SCAN_BS) void scan_block(const int* __restrict__ deg, int* __restrict__ tmp,
                                                      int* __restrict__ bsum, int n)
{
    __shared__ int sh[SCAN_BS];
    int gid = blockIdx.x * SCAN_BS + threadIdx.x;
    int v = (gid < n) ? deg[gid] : 0;
    sh[threadIdx.x] = v;
    __syncthreads();
    for (int o = 1; o < SCAN_BS; o <<= 1) {
        int add = (threadIdx.x >= o) ? sh[threadIdx.x - o] : 0;
        __syncthreads();
        sh[threadIdx.x] += add;
        __syncthreads();
    }
    if (gid < n) tmp[gid] = sh[threadIdx.x];
    if (threadIdx.x == SCAN_BS - 1) bsum[blockIdx.x] = sh[SCAN_BS - 1];
}

__global__ __launch_bounds__(SCAN_BS) void scan_bsum(int* __restrict__ bsum, int nb)
{
    __shared__ int sh[SCAN_BS];
    int v = (threadIdx.x < nb) ? bsum[threadIdx.x] : 0;
    sh[threadIdx.x] = v;
    __syncthreads();
    for (int o = 1; o < SCAN_BS; o <<= 1) {
        int add = (threadIdx.x >= o) ? sh[threadIdx.x - o] : 0;
        __syncthreads();
        sh[threadIdx.x] += add;
        __syncthreads();
    }
    if (threadIdx.x < nb) bsum[threadIdx.x] = sh[threadIdx.x];
}

__global__ __launch_bounds__(256) void scan_final(const int* __restrict__ tmp, const int* __restrict__ bsum,
                                                  const int* __restrict__ deg, int* __restrict__ offs,
                                                  int* __restrict__ cursor, int n)
{
    int gid = blockIdx.x * 256 + threadIdx.x;
    if (gid >= n) return;
    int b = gid / SCAN_BS;
    int inc = tmp[gid] + (b > 0 ? bsum[b - 1] : 0);
    offs[gid + 1] = inc;
    cursor[gid] = inc - deg[gid];
    if (gid == 0) offs[0] = 0;
}

__global__ __launch_bounds__(256) void csr_fill(const int* __restrict__ dst, int* __restrict__ cursor,
                                                int* __restrict__ perm, int E)
{
    int e = blockIdx.x * 256 + threadIdx.x;
    if (e < E) {
        int p = atomicAdd(&cursor[dst[e]], 1);
        perm[p] = e;
    }
}

// ---------------- pack CSR-ordered edges: ep[k] = src(perm[k])<<9 | bondkey(perm[k]) ----------------
__global__ __launch_bounds__(256) void pack_edges(
    const int* __restrict__ src, const int* __restrict__ eattr, const int* __restrict__ perm,
    u32* __restrict__ ep, int E)
{
    int k = blockIdx.x * 256 + threadIdx.x;
    if (k < E) {
        int eid = perm[k];
        int key = eattr[eid * 3 + 0] + (eattr[eid * 3 + 1] << 3) + (eattr[eid * 3 + 2] << 6);
        ep[k] = ((u32)src[eid] << 9) | (u32)key;
    }
}

// ---------------- aggregation: out_b[n] = bf16( hF[n] + sum_{e: dst==n} relu(h_b[src]+ebtab[key]) ) ----
__global__ __launch_bounds__(192) void aggregate(
    const u16* __restrict__ h, const u16* __restrict__ ebtab,
    const u32* __restrict__ ep, const int* __restrict__ offs,
    const float* __restrict__ hF, u16* __restrict__ out)
{
    long n = blockIdx.x;
    int t = threadIdx.x;           // 192 threads x 4 cols = 768
    int d = t * 4;
    float4 a = *reinterpret_cast<const float4*>(hF + n * DM + d);
    float acc0 = a.x, acc1 = a.y, acc2 = a.z, acc3 = a.w;
    int beg = offs[n], end = offs[n + 1];
    for (int k = beg; k < end; k++) {
        u32 pk = ep[k];
        long s = pk >> 9;
        long key = pk & 511;
        ushort4 hv = *reinterpret_cast<const ushort4*>(h + s * DM + d);
        ushort4 ev = *reinterpret_cast<const ushort4*>(ebtab + key * DM + d);
        acc0 += fmaxf(0.f, bf2f(hv.x) + bf2f(ev.x));
        acc1 += fmaxf(0.f, bf2f(hv.y) + bf2f(ev.y));
        acc2 += fmaxf(0.f, bf2f(hv.z) + bf2f(ev.z));
        acc3 += fmaxf(0.f, bf2f(hv.w) + bf2f(ev.w));
    }
    ushort4 o;
    o.x = f2bf(acc0); o.y = f2bf(acc1); o.z = f2bf(acc2); o.w = f2bf(acc3);
    *reinterpret_cast<ushort4*>(out + n * DM + d) = o;
}

// ---------------- GEMM: C[M,768] = act(A[M,768] @ W + bias) ; A bf16, Bt = W^T bf16 ----------------
// ACT: 0 none, 1 relu, 2 gelu.
// OUTM: 0 bf16 out via LDS-coalesced epilogue; 1 f32 direct (guarded); 2 both.
union GemmSmem {
    u16 tiles[2][2][128 * 32];   // [buf][A/B][row*32+k]
    u16 ctile[128 * 136];        // epilogue re-stage, padded stride (272B = 17*16B)
};

template <int ACT, int OUTM>
__global__ __launch_bounds__(256) void gemm128(
    const u16* __restrict__ A, const u16* __restrict__ Bt,
    const float* __restrict__ bias,
    u16* __restrict__ outB, float* __restrict__ outF, int Mvalid)
{
    __shared__ GemmSmem sm;
    const int tid = threadIdx.x;
    const int lane = tid & 63, wid = tid >> 6;
    const int wr = wid >> 1, wc = wid & 1;

    // XCD-chunked bijective block swizzle (m204)
    const int nwg = gridDim.x;
    const int orig = blockIdx.x;
    const int q8 = nwg >> 3, r8 = nwg & 7;
    const int xcd = orig & 7, idx8 = orig >> 3;
    const int w = (xcd < r8 ? xcd * (q8 + 1) : r8 * (q8 + 1) + (xcd - r8) * q8) + idx8;
    const int n0 = (w % 6) * 128;
    const long m0 = (long)(w / 6) * 128;

    f32x4 acc[4][4] = {};

    // staging: 512 chunks of 16B per tile; chunk c -> row=c>>2, kb_phys=c&3.
    // source reads logical kb = kb_phys ^ ((row>>1)&3)  (XOR involution, dest linear)
    const int ch0 = tid, ch1 = 256 + tid;
    const int r0_ = ch0 >> 2, k0_ = (ch0 & 3) ^ ((r0_ >> 1) & 3);
    const int r1_ = ch1 >> 2, k1_ = (ch1 & 3) ^ ((r1_ >> 1) & 3);
    const u16* Ag0 = A + (m0 + r0_) * DM + k0_ * 8;
    const u16* Ag1 = A + (m0 + r1_) * DM + k1_ * 8;
    const u16* Bg0 = Bt + (long)(n0 + r0_) * DM + k0_ * 8;
    const u16* Bg1 = Bt + (long)(n0 + r1_) * DM + k1_ * 8;
    const int lds0 = ((wid << 6)) * 8;
    const int lds1 = (256 + (wid << 6)) * 8;

    auto stage = [&](int buf, int kt) {
        int ko = kt * 32;
        __builtin_amdgcn_global_load_lds((gvoid*)(Ag0 + ko), (lvoid*)&sm.tiles[buf][0][lds0], 16, 0, 0);
        __builtin_amdgcn_global_load_lds((gvoid*)(Ag1 + ko), (lvoid*)&sm.tiles[buf][0][lds1], 16, 0, 0);
        __builtin_amdgcn_global_load_lds((gvoid*)(Bg0 + ko), (lvoid*)&sm.tiles[buf][1][lds0], 16, 0, 0);
        __builtin_amdgcn_global_load_lds((gvoid*)(Bg1 + ko), (lvoid*)&sm.tiles[buf][1][lds1], 16, 0, 0);
    };

    stage(0, 0);
    asm volatile("s_waitcnt vmcnt(0)" ::: "memory");
    __syncthreads();

    const int ar = lane & 15, kb = lane >> 4;
    const int kbe = kb ^ ((ar >> 1) & 3);   // read-side XOR (m,wr-invariant)
    int cur = 0;
    for (int kt = 0; kt < DM / 32; ++kt) {
        if (kt + 1 < DM / 32) stage(cur ^ 1, kt + 1);
        bf16x8 af[4], bv[4];
        #pragma unroll
        for (int m = 0; m < 4; m++)
            af[m] = *reinterpret_cast<const bf16x8*>(&sm.tiles[cur][0][(wr * 64 + m * 16 + ar) * 32 + kbe * 8]);
        #pragma unroll
        for (int n = 0; n < 4; n++)
            bv[n] = *reinterpret_cast<const bf16x8*>(&sm.tiles[cur][1][(wc * 64 + n * 16 + ar) * 32 + kbe * 8]);
        #pragma unroll
        for (int m = 0; m < 4; m++)
            #pragma unroll
            for (int n = 0; n < 4; n++)
                acc[m][n] = __builtin_amdgcn_mfma_f32_16x16x32_bf16(af[m], bv[n], acc[m][n], 0, 0, 0);
        asm volatile("s_waitcnt vmcnt(0)" ::: "memory");
        __syncthreads();
        cur ^= 1;
    }

    const int rg4 = (lane >> 4) * 4;
    if (OUTM == 1) {
        // f32 direct: 16 lanes x 4B = full 64B lines per row-group
        #pragma unroll
        for (int n = 0; n < 4; n++) {
            int col = n0 + wc * 64 + n * 16 + ar;
            float bvp = bias[col];
            #pragma unroll
            for (int m = 0; m < 4; m++) {
                long rb = m0 + wr * 64 + m * 16 + rg4;
                #pragma unroll
                for (int j = 0; j < 4; j++) {
                    float v = acc[m][n][j] + bvp;
                    if (ACT == 1) v = fmaxf(v, 0.f);
                    if (ACT == 2) v = gelu_f(v);
                    long row = rb + j;
                    if (row < Mvalid) outF[row * DM + col] = v;
                }
            }
        }
    } else {
        // bf16 via LDS re-stage -> coalesced 16B stores; f32 (OUTM==2) direct
        #pragma unroll
        for (int n = 0; n < 4; n++) {
            int lc = wc * 64 + n * 16 + ar;
            float bvp = bias[n0 + lc];
            #pragma unroll
            for (int m = 0; m < 4; m++) {
                int lr = wr * 64 + m * 16 + rg4;
                #pragma unroll
                for (int j = 0; j < 4; j++) {
                    float v = acc[m][n][j] + bvp;
                    if (ACT == 1) v = fmaxf(v, 0.f);
                    if (ACT == 2) v = gelu_f(v);
                    sm.ctile[(lr + j) * 136 + lc] = f2bf(v);
                    if (OUTM == 2) {
                        long row = m0 + lr + j;
                        if (row < Mvalid) outF[row * DM + n0 + lc] = v;
                    }
                }
            }
        }
        __syncthreads();
        const int row = tid >> 1, hh = tid & 1;
        const u16* srcp = &sm.ctile[row * 136 + hh * 64];
        u16* dstp = outB + (m0 + row) * DM + n0 + hh * 64;
        #pragma unroll
        for (int i = 0; i < 8; i++)
            *reinterpret_cast<uint4*>(dstp + i * 8) = *reinterpret_cast<const uint4*>(srcp + i * 8);
    }
}

extern "C" void kernel_launch(void* const* d_in, const int* in_sizes, int n_in,
                              void* d_out, int out_size, void* d_ws, size_t ws_size,
                              hipStream_t stream)
{
    const int N = in_sizes[0] / 9;
    const int E = in_sizes[1] / 3;
    const int L = 4;
    const long Mpad = ((N + 127) / 128) * 128;
    const int Mtiles = (int)(Mpad / 128);

    const int* x = (const int*)d_in[0];
    const int* eattr = (const int*)d_in[1];
    const int* eidx = (const int*)d_in[2];
    const float* atom_emb = (const float*)d_in[3];
    const float* atom_g = (const float*)d_in[4];
    const float* atom_bb = (const float*)d_in[5];
    const float* atom_w1 = (const float*)d_in[6];
    const float* atom_b1 = (const float*)d_in[7];
    const float* atom_w2 = (const float*)d_in[8];
    const float* atom_b2 = (const float*)d_in[9];
    const float* bond_emb = (const float*)d_in[10];
    const float* bond_g = (const float*)d_in[11];
    const float* bond_bb = (const float*)d_in[12];
    const float* bond_w1 = (const float*)d_in[13];
    const float* bond_b1 = (const float*)d_in[14];
    const float* bond_w2 = (const float*)d_in[15];
    const float* bond_b2 = (const float*)d_in[16];
    const float* conv_w1 = (const float*)d_in[17];
    const float* conv_b1 = (const float*)d_in[18];
    const float* conv_w2 = (const float*)d_in[19];
    const float* conv_b2 = (const float*)d_in[20];
    const float* ln_g = (const float*)d_in[21];
    const float* ln_b = (const float*)d_in[22];
    const int* src = eidx;
    const int* dst = eidx + E;
    float* nodeF = (float*)d_out;   // node-f32 buffer: f32 h / GEMM f32 out, final output

    char* p = (char*)d_ws;
    auto alloc = [&](size_t bytes) { void* r = (void*)p; p += (bytes + 255) & ~(size_t)255; return r; };
    u16* B2   = (u16*)alloc((size_t)2 * Mpad * DM * 2);   // node bf16 ping-pong
    u16* h_b  = (u16*)alloc((size_t)Mpad * DM * 2);
    u16* wbt  = (u16*)alloc((size_t)12 * DM * DM * 2);
    u16* bt0  = (u16*)alloc((size_t)512 * DM * 2);
    u16* bt1  = (u16*)alloc((size_t)512 * DM * 2);
    u16* ebtab= (u16*)alloc((size_t)512 * DM * 2);
    int* deg    = (int*)alloc((size_t)N * 4);
    int* tmp    = (int*)alloc((size_t)N * 4);
    int* cursor = (int*)alloc((size_t)N * 4);
    int* offs   = (int*)alloc((size_t)(N + 1) * 4);
    int* bsum   = (int*)alloc((size_t)SCAN_BS * 4);
    int* perm   = (int*)alloc((size_t)E * 4);
    u32* ep     = (u32*)alloc((size_t)E * 4);
    u16* B2a = B2;
    u16* B2b = B2 + (size_t)Mpad * DM;

    // ---- CSR build (counting sort by dst) + packed edge records ----
    hipMemsetAsync(deg, 0, (size_t)N * 4, stream);
    csr_count<<<(E + 255) / 256, 256, 0, stream>>>(dst, deg, E);
    const int nb = (N + SCAN_BS - 1) / SCAN_BS;
    scan_block<<<nb, SCAN_BS, 0, stream>>>(deg, tmp, bsum, N);
    scan_bsum<<<1, SCAN_BS, 0, stream>>>(bsum, nb);
    scan_final<<<(N + 255) / 256, 256, 0, stream>>>(tmp, bsum, deg, offs, cursor, N);
    csr_fill<<<(E + 255) / 256, 256, 0, stream>>>(dst, cursor, perm, E);
    pack_edges<<<(E + 255) / 256, 256, 0, stream>>>(src, eattr, perm, ep, E);

    // weight prep (12 matrices, transpose + bf16)
    prep_weights<<<dim3(24, 24, 12), 256, 0, stream>>>(atom_w1, atom_w2, bond_w1, bond_w2, conv_w1, conv_w2, wbt);

    // bond encoder on the 512-key table only
    encode_ln_bond<<<512, 256, 0, stream>>>(bond_emb, bond_g, bond_bb, bt0);
    gemm128<2, 0><<<6 * 4, 256, 0, stream>>>(bt0, wbt + (size_t)2 * DM * DM, bond_b1, bt1, nullptr, 0);
    gemm128<0, 0><<<6 * 4, 256, 0, stream>>>(bt1, wbt + (size_t)3 * DM * DM, bond_b2, ebtab, nullptr, 0);

    // atom encoder: emb-sum+LN -> B2a; GEMM1(gelu) B2a->B2b; GEMM2 -> h_b (bf16) + nodeF (f32 h, guarded)
    encode_ln<<<N, 256, 0, stream>>>(x, 9, 64, atom_emb, atom_g, atom_bb, B2a);
    gemm128<2, 0><<<6 * Mtiles, 256, 0, stream>>>(B2a, wbt + (size_t)0 * DM * DM, atom_b1, B2b, nullptr, 0);
    gemm128<0, 2><<<6 * Mtiles, 256, 0, stream>>>(B2b, wbt + (size_t)1 * DM * DM, atom_b2, h_b, nodeF, N);

    // GNN layers
    for (int l = 0; l < L; l++) {
        aggregate<<<N, 192, 0, stream>>>(h_b, ebtab, ep, offs, nodeF, B2a);
        gemm128<1, 0><<<6 * Mtiles, 256, 0, stream>>>(B2a, wbt + (size_t)(4 + l) * DM * DM, conv_b1 + l * DM, B2b, nullptr, 0);
        gemm128<2, 1><<<6 * Mtiles, 256, 0, stream>>>(B2b, wbt + (size_t)(8 + l) * DM * DM, conv_b2 + l * DM, nullptr, nodeF, N);
        layer_ln<<<N, 256, 0, stream>>>(nodeF, h_b, ln_g + l * DM, ln_b + l * DM,
                                        (l == L - 1) ? nullptr : h_b, nodeF);
    }
}